// Round 10
// baseline (299.627 us; speedup 1.0000x reference)
//
#include <hip/hip_runtime.h>
#include <hip/hip_bf16.h>
#include <math.h>

// VQ quantizer: single-sweep bf16-MFMA prefilter + fp32-chain-exact rescore.
//   Exact semantics (validated r2/r4/r6): dist = fl32(fl32(r2+e2) - 2*fma_chain(x.e)),
//   argmin first-min-wins.
// Online-threshold capture (r8-validated): per-block LDS runmin (prefix min over
//   seen cols); capture c iff s(c) <= runmin + M. Any snapshot >= gmin, so all c
//   with mfma-score <= gmin + 2delta (~3e-4) are captured (M=6e-4) -> superset of
//   the needed set; races only loosen the threshold. Exact full-scan fallback on
//   cnt>CAP keeps the output deterministic regardless.
// Round 10 = round 9 resubmitted byte-identical (r9 failed on infra:
//   UnresponsiveContainer before the kernel ran; audit found no hang hazard).
//   Rb=128 rows/block (intensity 128 FLOP/B -> compute-bound vs L2),
//   double-buffered B tiles (Cb=64), 8 waves, A in registers, shfl thresholds.
// Outputs (float32 flat): [loss | quantized(8192*256) | indices(8192 as float)]

#define NROWS 8192
#define DDIM  256
#define KCW   8192
#define CAP   128
#define MARGIN 6e-4f
#define TILES 16      // 16 x 64 cols = 1024 cols per block (eighth sweep)

typedef __attribute__((ext_vector_type(8))) short short8;
typedef __attribute__((ext_vector_type(4))) float f32x4;
typedef unsigned int u32;

__device__ inline void async_copy16(void* lds_uniform, const void* gsrc) {
  __builtin_amdgcn_global_load_lds(
      (const __attribute__((address_space(1))) u32*)gsrc,
      (__attribute__((address_space(3))) u32*)lds_uniform, 16, 0, 0);
}

__device__ inline unsigned fmap(float f) {
  unsigned b = __float_as_uint(f);
  return (b & 0x80000000u) ? ~b : (b | 0x80000000u);
}
__device__ inline float funmap(unsigned u) {
  unsigned b = (u & 0x80000000u) ? (u & 0x7FFFFFFFu) : ~u;
  return __uint_as_float(b);
}

// Fused: bf16 cast + e2 (f64->f32, cb rows) + cnt init (z rows).
__global__ __launch_bounds__(256) void k_prep_cast(const float* __restrict__ z,
                                                   const float* __restrict__ cb,
                                                   ushort* __restrict__ zb,
                                                   ushort* __restrict__ cbb,
                                                   float* __restrict__ e2f,
                                                   unsigned* __restrict__ cnt) {
  int t = threadIdx.x, w = t >> 6, lane = t & 63;
  int wid = blockIdx.x * 4 + w;           // 0..16383
  bool isCb = wid >= NROWS;
  int row = isCb ? wid - NROWS : wid;
  const float* src = (isCb ? cb : z) + (size_t)row * DDIM + lane * 4;
  float4 v = *reinterpret_cast<const float4*>(src);
  ushort4 o;
  __hip_bfloat16 bx = __float2bfloat16(v.x); o.x = *(ushort*)&bx;
  __hip_bfloat16 by = __float2bfloat16(v.y); o.y = *(ushort*)&by;
  __hip_bfloat16 bz = __float2bfloat16(v.z); o.z = *(ushort*)&bz;
  __hip_bfloat16 bw = __float2bfloat16(v.w); o.w = *(ushort*)&bw;
  ushort* dst = (isCb ? cbb : zb) + (size_t)row * DDIM + lane * 4;
  *reinterpret_cast<ushort4*>(dst) = o;
  if (isCb) {
    double d = (double)v.x * v.x + (double)v.y * v.y + (double)v.z * v.z + (double)v.w * v.w;
#pragma unroll
    for (int off = 1; off < 64; off <<= 1) d += __shfl_xor(d, off);
    if (lane == 0) e2f[row] = (float)d;
  } else {
    if (lane == 0) cnt[row] = 0;
  }
}

// Block: 128 rows x 1024 cols (16 tiles of 64), 8 waves (4 row-groups x 2 col-groups).
// A (128x256 bf16) in registers (per wave: its 32 rows). B tile (64x256 bf16 = 32KB)
// double-buffered via global_load_lds (16B granules, slot-XOR pre-swizzled source —
// the r8-proven bijective pair).
__global__ __launch_bounds__(512, 2) void k_sweep(const ushort* __restrict__ zb,
                                                  const ushort* __restrict__ cbb,
                                                  const float* __restrict__ e2f,
                                                  unsigned* __restrict__ cnt,
                                                  ushort* __restrict__ cand) {
  __shared__ ushort Bb[2][64 * 256];     // 2 x 32KB, [col][k] with 16B-slot swizzle
  __shared__ unsigned runmin[128];
  int t = threadIdx.x, w = t >> 6, lane = t & 63;
  int wg = ((blockIdx.x & 7) << 6) | (blockIdx.x >> 3);   // XCD swizzle (512%8==0)
  int rt = wg >> 3, q = wg & 7;
  int R0 = rt * 128, C0 = q * 1024;
  int wm = w >> 1, wn = w & 1;
  int cl = lane & 15, g = lane >> 4;

  if (t < 128) runmin[t] = ~0u;

  // A preload: wave's 32 rows; lane holds A[wm*32+m*16+cl][kk*32+g*8 ..+8]
  short8 Areg[2][8];
#pragma unroll
  for (int m = 0; m < 2; ++m)
#pragma unroll
    for (int kk = 0; kk < 8; ++kk)
      Areg[m][kk] = *reinterpret_cast<const short8*>(
          &zb[(size_t)(R0 + wm * 32 + m * 16 + cl) * DDIM + kk * 32 + g * 8]);

  // stage tile 0 -> buf 0 (32 chunks of 1KB; wave w owns chunks i*8+w)
#pragma unroll
  for (int i = 0; i < 4; ++i) {
    int chunk = i * 8 + w;
    int col = chunk * 2 + (lane >> 5);
    const ushort* src = cbb + (size_t)(C0 + col) * DDIM + ((lane & 31) ^ (col & 7)) * 8;
    async_copy16((char*)Bb[0] + chunk * 1024, src);
  }
  __syncthreads();                        // drains stage(0); runmin init visible

  for (int tile = 0; tile < TILES; ++tile) {
    int cur = tile & 1;
    if (tile + 1 < TILES) {               // issue next-tile stage BEFORE compute
      int CTn = C0 + (tile + 1) * 64;
#pragma unroll
      for (int i = 0; i < 4; ++i) {
        int chunk = i * 8 + w;
        int col = chunk * 2 + (lane >> 5);
        const ushort* src = cbb + (size_t)(CTn + col) * DDIM + ((lane & 31) ^ (col & 7)) * 8;
        async_copy16((char*)Bb[cur ^ 1] + chunk * 1024, src);
      }
    }
    int CT = C0 + tile * 64;
    float e2v[2];
#pragma unroll
    for (int n = 0; n < 2; ++n) e2v[n] = e2f[CT + wn * 32 + n * 16 + cl];

    f32x4 acc[2][2];
#pragma unroll
    for (int m = 0; m < 2; ++m)
#pragma unroll
      for (int n = 0; n < 2; ++n) acc[m][n] = (f32x4){0.f, 0.f, 0.f, 0.f};
#pragma unroll
    for (int kk = 0; kk < 8; ++kk) {
      short8 bfrag[2];
#pragma unroll
      for (int n = 0; n < 2; ++n) {
        int col = wn * 32 + n * 16 + cl;
        int addr = col * 512 + (((kk * 4 + g) ^ (col & 7)) << 4);
        bfrag[n] = *reinterpret_cast<const short8*>((char*)Bb[cur] + addr);
      }
#pragma unroll
      for (int m = 0; m < 2; ++m)
#pragma unroll
        for (int n = 0; n < 2; ++n)
          acc[m][n] = __builtin_amdgcn_mfma_f32_16x16x32_bf16(Areg[m][kk], bfrag[n], acc[m][n], 0, 0, 0);
    }

    // scores; C/D layout col=lane&15, row=(lane>>4)*4+j [m89/m91]
    float sc[2][2][4];
#pragma unroll
    for (int m = 0; m < 2; ++m)
#pragma unroll
      for (int n = 0; n < 2; ++n)
#pragma unroll
        for (int j = 0; j < 4; ++j)
          sc[m][n][j] = __fsub_rn(e2v[n], __fmul_rn(2.0f, acc[m][n][j]));

    // runmin update per (m,j): min over n(2) and 16 cl-lanes -> LDS atomicMin
#pragma unroll
    for (int m = 0; m < 2; ++m)
#pragma unroll
      for (int j = 0; j < 4; ++j) {
        float mn = fminf(sc[m][0][j], sc[m][1][j]);
#pragma unroll
        for (int off = 1; off < 16; off <<= 1) mn = fminf(mn, __shfl_xor(mn, off));
        if (cl == 0) atomicMin(&runmin[wm * 32 + m * 16 + g * 4 + j], fmap(mn));
      }
    // thresholds: one conflict-free b32 read + shfl distribution (no broadcasts)
    int rmv = (int)runmin[wm * 32 + (lane & 31)];
#pragma unroll
    for (int m = 0; m < 2; ++m)
#pragma unroll
      for (int j = 0; j < 4; ++j) {
        int rloc = m * 16 + g * 4 + j;                   // 0..31 within wave rows
        float thr = funmap((unsigned)__shfl(rmv, rloc)) + MARGIN;
#pragma unroll
        for (int n = 0; n < 2; ++n) {
          if (sc[m][n][j] <= thr) {
            int row = R0 + wm * 32 + rloc;
            unsigned slot = atomicAdd(&cnt[row], 1u);
            if (slot < CAP) cand[(size_t)row * CAP + slot] = (ushort)(CT + wn * 32 + n * 16 + cl);
          }
        }
      }
    __syncthreads();    // buf[cur] consumed by all; drains next-tile stage
  }
}

// Fused: exact fp32-chain rescore (lex (s,idx) min = first-min-wins) + overflow
// full-scan fallback + gather + per-row loss partial. r2 computed inline.
__global__ __launch_bounds__(256) void k_rescore_gather(const float* __restrict__ z,
                                                        const float* __restrict__ cb,
                                                        const float* __restrict__ e2f,
                                                        const unsigned* __restrict__ cnt,
                                                        const ushort* __restrict__ cand,
                                                        float* __restrict__ out_q,
                                                        float* __restrict__ out_idx,
                                                        float* __restrict__ lpart) {
  int t = threadIdx.x, w = t >> 6, lane = t & 63;
  int row = blockIdx.x * 4 + w;
  const float* xp = z + (size_t)row * DDIM;
  float4 x4 = *reinterpret_cast<const float4*>(xp + lane * 4);
  double rd = (double)x4.x * x4.x + (double)x4.y * x4.y + (double)x4.z * x4.z + (double)x4.w * x4.w;
#pragma unroll
  for (int off = 1; off < 64; off <<= 1) rd += __shfl_xor(rd, off);
  float r2v = (float)rd;                  // same summation as r6's k_prep (validated)

  unsigned n = cnt[row];
  float s = INFINITY; int ci = 0x7fffffff;
  if (n <= CAP) {
#pragma unroll
    for (int base = 0; base < CAP; base += 64) {
      int k_i = base + lane;
      if (k_i < (int)n) {
        int c = cand[(size_t)row * CAP + k_i];
        const float* ep = cb + (size_t)c * DDIM;
        float acc = 0.f;
        for (int k = 0; k < DDIM; ++k) acc = __fmaf_rn(xp[k], ep[k], acc);  // k ascending
        float scv = __fsub_rn(__fadd_rn(r2v, e2f[c]), __fmul_rn(2.0f, acc));
        if (scv < s || (scv == s && c < ci)) { s = scv; ci = c; }
      }
    }
  } else {
    for (int base = 0; base < KCW; base += 64) {      // exact full-scan fallback
      int c = base + lane;
      const float* ep = cb + (size_t)c * DDIM;
      float acc = 0.f;
      for (int k = 0; k < DDIM; ++k) acc = __fmaf_rn(xp[k], ep[k], acc);
      float scv = __fsub_rn(__fadd_rn(r2v, e2f[c]), __fmul_rn(2.0f, acc));
      if (scv < s) { s = scv; ci = c; }               // c ascending: first-wins
    }
  }
#pragma unroll
  for (int off = 1; off < 64; off <<= 1) {            // butterfly: all lanes get min
    float os = __shfl_xor(s, off); int oi = __shfl_xor(ci, off);
    if (os < s || (os == s && oi < ci)) { s = os; ci = oi; }
  }
  if (lane == 0) out_idx[row] = (float)ci;

  float4 qv = *reinterpret_cast<const float4*>(cb + (size_t)ci * DDIM + lane * 4);
  float* o = out_q + (size_t)row * DDIM + lane * 4;   // out+1 base: scalar stores
  o[0] = qv.x; o[1] = qv.y; o[2] = qv.z; o[3] = qv.w;
  float dx = qv.x - x4.x, dy = qv.y - x4.y, dz = qv.z - x4.z, dw = qv.w - x4.w;
  double d = (double)dx * dx + (double)dy * dy + (double)dz * dz + (double)dw * dw;
#pragma unroll
  for (int off = 1; off < 64; off <<= 1) d += __shfl_xor(d, off);
  if (lane == 0) lpart[row] = (float)d;
}

__global__ __launch_bounds__(256) void k_loss(const float* __restrict__ lpart,
                                              float* __restrict__ out0) {
  __shared__ double red[256];
  int t = threadIdx.x;
  double s = 0.0;
  for (int j = t; j < NROWS; j += 256) s += lpart[j];  // fixed order -> deterministic
  red[t] = s;
  __syncthreads();
  for (int off = 128; off > 0; off >>= 1) {
    if (t < off) red[t] += red[t + off];
    __syncthreads();
  }
  if (t == 0) out0[0] = (float)(1.25 * red[0] / (double)((size_t)NROWS * DDIM));
}

extern "C" void kernel_launch(void* const* d_in, const int* in_sizes, int n_in,
                              void* d_out, int out_size, void* d_ws, size_t ws_size,
                              hipStream_t stream) {
  const float* z  = (const float*)d_in[0];   // [16,512,256] flat
  const float* cb = (const float*)d_in[1];   // [8192,256]
  float* out = (float*)d_out;
  char* ws = (char*)d_ws;
  const size_t HALF = (size_t)NROWS * DDIM;  // 2,097,152

  // bf16 copies in the out_q region (out+4 floats: 16B-aligned). Last 3 floats
  // of cbb overlap out_idx[0..2]; out_idx is written by k_rescore_gather, which
  // runs after the last zb/cbb read (k_sweep). Recomputed every call.
  ushort* zb  = (ushort*)(out + 4);
  ushort* cbb = zb + HALF;

  // ws: e2f 32K | cnt 32K | lpart 32K | cand ushort 8192*128*2 = 2MB
  // total 2,195,456 B  (< 2,211,840 proven in round 2)
  size_t off = 0;
  float*    e2f   = (float*)(ws + off);    off += NROWS * 4;
  unsigned* cnt   = (unsigned*)(ws + off); off += NROWS * 4;
  float*    lpart = (float*)(ws + off);    off += NROWS * 4;
  ushort*   cand  = (ushort*)(ws + off);   off += (size_t)NROWS * CAP * 2;

  float* out_q   = out + 1;
  float* out_idx = out + 1 + HALF;

  k_prep_cast     <<<(2 * NROWS) / 4, 256, 0, stream>>>(z, cb, zb, cbb, e2f, cnt);
  k_sweep         <<<512,             512, 0, stream>>>(zb, cbb, e2f, cnt, cand);
  k_rescore_gather<<<NROWS / 4,       256, 0, stream>>>(z, cb, e2f, cnt, cand, out_q, out_idx, lpart);
  k_loss          <<<1,               256, 0, stream>>>(lpart, out);
}

// Round 11
// 208.695 us; speedup vs baseline: 1.4357x; 1.4357x over previous
//
#include <hip/hip_runtime.h>
#include <hip/hip_bf16.h>
#include <math.h>

// VQ quantizer: LDS-free register-sweep bf16-MFMA prefilter + fp32-chain-exact rescore.
//   Exact semantics (validated r2/r4/r6): dist = fl32(fl32(r2+e2) - 2*fma_chain(x.e)),
//   argmin first-min-wins.
// Swapped-operand MFMA: mfma(A=cb_frag, B=z_frag) puts z-row on lane&15 ->
//   per-row running min is in-lane fmin + 2 shfl (no LDS, no barriers).
// Capture rule: s(c) <= runmin + M, runmin = per-row prefix min, cross-wave
//   shared via device atomicMin(rowMinU) (any shared value >= true min -> capture
//   set is a superset of all c with s_mfma(c) <= gmin + 2delta; 2delta~3e-4 <= M=5e-4;
//   stale cross-XCD reads only loosen -> safe). CAP=128; exact full-scan fallback
//   on overflow keeps output deterministic regardless.
// Outputs (float32 flat): [loss | quantized(8192*256) | indices(8192 as float)]

#define NROWS 8192
#define DDIM  256
#define KCW   8192
#define CAP   128
#define MARGIN 5e-4f

typedef __attribute__((ext_vector_type(8))) short short8;
typedef __attribute__((ext_vector_type(4))) float f32x4;

__device__ inline unsigned fmap(float f) {
  unsigned b = __float_as_uint(f);
  return (b & 0x80000000u) ? ~b : (b | 0x80000000u);
}
__device__ inline float funmap(unsigned u) {
  unsigned b = (u & 0x80000000u) ? (u & 0x7FFFFFFFu) : ~u;
  return __uint_as_float(b);
}

// Fused: bf16 cast + e2 (f64->f32, cb rows) + rowMinU/cnt init (z rows).
__global__ __launch_bounds__(256) void k_prep_cast(const float* __restrict__ z,
                                                   const float* __restrict__ cb,
                                                   ushort* __restrict__ zb,
                                                   ushort* __restrict__ cbb,
                                                   float* __restrict__ e2f,
                                                   unsigned* __restrict__ rowMinU,
                                                   unsigned* __restrict__ cnt) {
  int t = threadIdx.x, w = t >> 6, lane = t & 63;
  int wid = blockIdx.x * 4 + w;           // 0..16383
  bool isCb = wid >= NROWS;
  int row = isCb ? wid - NROWS : wid;
  const float* src = (isCb ? cb : z) + (size_t)row * DDIM + lane * 4;
  float4 v = *reinterpret_cast<const float4*>(src);
  ushort4 o;
  __hip_bfloat16 bx = __float2bfloat16(v.x); o.x = *(ushort*)&bx;
  __hip_bfloat16 by = __float2bfloat16(v.y); o.y = *(ushort*)&by;
  __hip_bfloat16 bz = __float2bfloat16(v.z); o.z = *(ushort*)&bz;
  __hip_bfloat16 bw = __float2bfloat16(v.w); o.w = *(ushort*)&bw;
  ushort* dst = (isCb ? cbb : zb) + (size_t)row * DDIM + lane * 4;
  *reinterpret_cast<ushort4*>(dst) = o;
  if (isCb) {
    double d = (double)v.x * v.x + (double)v.y * v.y + (double)v.z * v.z + (double)v.w * v.w;
#pragma unroll
    for (int off = 1; off < 64; off <<= 1) d += __shfl_xor(d, off);
    if (lane == 0) e2f[row] = (float)d;
  } else {
    if (lane == 0) { rowMinU[row] = ~0u; cnt[row] = 0; }
  }
}

// Wave: 64 z-rows (4 n-frags x 16 on lane&15), sweeps 512 cb-cols (32 tiles of 16).
// z resident in 128 VGPR; cb fragments stream global->VGPR (16 rows x 64B lines).
// No LDS, no barriers. wid = rg*16 + sg: rg = 64-row group, sg = 512-col segment.
__global__ __launch_bounds__(256, 2) void k_sweep(const ushort* __restrict__ zb,
                                                  const ushort* __restrict__ cbb,
                                                  const float* __restrict__ e2f,
                                                  unsigned* __restrict__ rowMinU,
                                                  unsigned* __restrict__ cnt,
                                                  ushort* __restrict__ cand) {
  int t = threadIdx.x, w = t >> 6, lane = t & 63;
  int wid = blockIdx.x * 4 + w;           // 0..2047
  int rg = wid >> 4, sg = wid & 15;
  int R0 = rg * 64, C0 = sg * 512;
  int cl = lane & 15, g = lane >> 4;

  // z preload: B-frag layout (z-row on cl, k = kk*32 + g*8)
  short8 Z[4][8];
#pragma unroll
  for (int n = 0; n < 4; ++n)
#pragma unroll
    for (int kk = 0; kk < 8; ++kk)
      Z[n][kk] = *reinterpret_cast<const short8*>(
          &zb[(size_t)(R0 + n * 16 + cl) * DDIM + kk * 32 + g * 8]);

  int rowIdx[4];
#pragma unroll
  for (int n = 0; n < 4; ++n) rowIdx[n] = R0 + n * 16 + cl;

  float runm[4] = {INFINITY, INFINITY, INFINITY, INFINITY};

  for (int tile = 0; tile < 32; ++tile) {
    int CT = C0 + tile * 16;
    // cb A-frag: cb-col on cl, k = kk*32 + g*8
    short8 A[8];
#pragma unroll
    for (int kk = 0; kk < 8; ++kk)
      A[kk] = *reinterpret_cast<const short8*>(
          &cbb[(size_t)(CT + cl) * DDIM + kk * 32 + g * 8]);
    f32x4 e2v = *reinterpret_cast<const f32x4*>(&e2f[CT + g * 4]);

    f32x4 acc[4];
#pragma unroll
    for (int n = 0; n < 4; ++n) acc[n] = (f32x4){0.f, 0.f, 0.f, 0.f};
#pragma unroll
    for (int kk = 0; kk < 8; ++kk)
#pragma unroll
      for (int n = 0; n < 4; ++n)
        acc[n] = __builtin_amdgcn_mfma_f32_16x16x32_bf16(A[kk], Z[n][kk], acc[n], 0, 0, 0);

    // D layout: M-idx (cb-col offset) = g*4+j, N-idx (z-row) = cl  [swapped r7 mapping]
#pragma unroll
    for (int n = 0; n < 4; ++n) {
      float s0 = __fsub_rn(e2v[0], __fmul_rn(2.0f, acc[n][0]));
      float s1 = __fsub_rn(e2v[1], __fmul_rn(2.0f, acc[n][1]));
      float s2 = __fsub_rn(e2v[2], __fmul_rn(2.0f, acc[n][2]));
      float s3 = __fsub_rn(e2v[3], __fmul_rn(2.0f, acc[n][3]));
      float jm = fminf(fminf(s0, s1), fminf(s2, s3));
      jm = fminf(jm, __shfl_xor(jm, 16));   // reduce over g (4 lanes, same cl)
      jm = fminf(jm, __shfl_xor(jm, 32));
      runm[n] = fminf(runm[n], jm);
      float thr = runm[n] + MARGIN;
      int row = rowIdx[n];
      int colb = CT + g * 4;
      if (s0 <= thr) { unsigned sl = atomicAdd(&cnt[row], 1u); if (sl < CAP) cand[(size_t)row * CAP + sl] = (ushort)(colb + 0); }
      if (s1 <= thr) { unsigned sl = atomicAdd(&cnt[row], 1u); if (sl < CAP) cand[(size_t)row * CAP + sl] = (ushort)(colb + 1); }
      if (s2 <= thr) { unsigned sl = atomicAdd(&cnt[row], 1u); if (sl < CAP) cand[(size_t)row * CAP + sl] = (ushort)(colb + 2); }
      if (s3 <= thr) { unsigned sl = atomicAdd(&cnt[row], 1u); if (sl < CAP) cand[(size_t)row * CAP + sl] = (ushort)(colb + 3); }
    }

    // cross-wave threshold sharing (early-heavy cadence: tiles 0,1,7,15,23,31)
    if (tile < 2 || (tile & 7) == 7) {
#pragma unroll
      for (int n = 0; n < 4; ++n) {
        if (g == n) atomicMin(&rowMinU[rowIdx[n]], fmap(runm[n]));
      }
#pragma unroll
      for (int n = 0; n < 4; ++n)
        runm[n] = fminf(runm[n], funmap(rowMinU[rowIdx[n]]));   // stale -> looser -> safe
    }
  }
}

// Fused: exact fp32-chain rescore (lex (s,idx) min = first-min-wins) + overflow
// full-scan fallback + gather + per-row loss partial. r2 computed inline.
__global__ __launch_bounds__(256) void k_rescore_gather(const float* __restrict__ z,
                                                        const float* __restrict__ cb,
                                                        const float* __restrict__ e2f,
                                                        const unsigned* __restrict__ cnt,
                                                        const ushort* __restrict__ cand,
                                                        float* __restrict__ out_q,
                                                        float* __restrict__ out_idx,
                                                        float* __restrict__ lpart) {
  int t = threadIdx.x, w = t >> 6, lane = t & 63;
  int row = blockIdx.x * 4 + w;
  const float* xp = z + (size_t)row * DDIM;
  float4 x4 = *reinterpret_cast<const float4*>(xp + lane * 4);
  double rd = (double)x4.x * x4.x + (double)x4.y * x4.y + (double)x4.z * x4.z + (double)x4.w * x4.w;
#pragma unroll
  for (int off = 1; off < 64; off <<= 1) rd += __shfl_xor(rd, off);
  float r2v = (float)rd;                  // same summation as r6's k_prep (validated)

  unsigned n = cnt[row];
  float s = INFINITY; int ci = 0x7fffffff;
  if (n <= CAP) {
#pragma unroll
    for (int base = 0; base < CAP; base += 64) {
      int k_i = base + lane;
      if (k_i < (int)n) {
        int c = cand[(size_t)row * CAP + k_i];
        const float* ep = cb + (size_t)c * DDIM;
        float acc = 0.f;
        for (int k = 0; k < DDIM; ++k) acc = __fmaf_rn(xp[k], ep[k], acc);  // k ascending
        float scv = __fsub_rn(__fadd_rn(r2v, e2f[c]), __fmul_rn(2.0f, acc));
        if (scv < s || (scv == s && c < ci)) { s = scv; ci = c; }
      }
    }
  } else {
    for (int base = 0; base < KCW; base += 64) {      // exact full-scan fallback
      int c = base + lane;
      const float* ep = cb + (size_t)c * DDIM;
      float acc = 0.f;
      for (int k = 0; k < DDIM; ++k) acc = __fmaf_rn(xp[k], ep[k], acc);
      float scv = __fsub_rn(__fadd_rn(r2v, e2f[c]), __fmul_rn(2.0f, acc));
      if (scv < s) { s = scv; ci = c; }               // c ascending: first-wins
    }
  }
#pragma unroll
  for (int off = 1; off < 64; off <<= 1) {            // butterfly: all lanes get min
    float os = __shfl_xor(s, off); int oi = __shfl_xor(ci, off);
    if (os < s || (os == s && oi < ci)) { s = os; ci = oi; }
  }
  if (lane == 0) out_idx[row] = (float)ci;

  float4 qv = *reinterpret_cast<const float4*>(cb + (size_t)ci * DDIM + lane * 4);
  float* o = out_q + (size_t)row * DDIM + lane * 4;   // out+1 base: scalar stores
  o[0] = qv.x; o[1] = qv.y; o[2] = qv.z; o[3] = qv.w;
  float dx = qv.x - x4.x, dy = qv.y - x4.y, dz = qv.z - x4.z, dw = qv.w - x4.w;
  double d = (double)dx * dx + (double)dy * dy + (double)dz * dz + (double)dw * dw;
#pragma unroll
  for (int off = 1; off < 64; off <<= 1) d += __shfl_xor(d, off);
  if (lane == 0) lpart[row] = (float)d;
}

__global__ __launch_bounds__(256) void k_loss(const float* __restrict__ lpart,
                                              float* __restrict__ out0) {
  __shared__ double red[256];
  int t = threadIdx.x;
  double s = 0.0;
  for (int j = t; j < NROWS; j += 256) s += lpart[j];  // fixed order -> deterministic
  red[t] = s;
  __syncthreads();
  for (int off = 128; off > 0; off >>= 1) {
    if (t < off) red[t] += red[t + off];
    __syncthreads();
  }
  if (t == 0) out0[0] = (float)(1.25 * red[0] / (double)((size_t)NROWS * DDIM));
}

extern "C" void kernel_launch(void* const* d_in, const int* in_sizes, int n_in,
                              void* d_out, int out_size, void* d_ws, size_t ws_size,
                              hipStream_t stream) {
  const float* z  = (const float*)d_in[0];   // [16,512,256] flat
  const float* cb = (const float*)d_in[1];   // [8192,256]
  float* out = (float*)d_out;
  char* ws = (char*)d_ws;
  const size_t HALF = (size_t)NROWS * DDIM;  // 2,097,152

  // bf16 copies in the out_q region (out+4 floats: 16B-aligned). Last 3 floats
  // of cbb overlap out_idx[0..2]; out_idx is written by k_rescore_gather, which
  // runs after the last zb/cbb read (k_sweep). Recomputed every call.
  ushort* zb  = (ushort*)(out + 4);
  ushort* cbb = zb + HALF;

  // ws: e2f 32K | cnt 32K | rowMinU 32K (lpart overlays it after k_sweep) |
  //     cand ushort 8192*128*2 = 2MB ; total 2,195,456 B (< 2,211,840 proven in r2)
  size_t off = 0;
  float*    e2f     = (float*)(ws + off);    off += NROWS * 4;
  unsigned* cnt     = (unsigned*)(ws + off); off += NROWS * 4;
  unsigned* rowMinU = (unsigned*)(ws + off);
  float*    lpart   = (float*)(ws + off);    off += NROWS * 4;   // overlays rowMinU
  ushort*   cand    = (ushort*)(ws + off);   off += (size_t)NROWS * CAP * 2;

  float* out_q   = out + 1;
  float* out_idx = out + 1 + HALF;

  k_prep_cast     <<<(2 * NROWS) / 4, 256, 0, stream>>>(z, cb, zb, cbb, e2f, rowMinU, cnt);
  k_sweep         <<<512,             256, 0, stream>>>(zb, cbb, e2f, rowMinU, cnt, cand);
  k_rescore_gather<<<NROWS / 4,       256, 0, stream>>>(z, cb, e2f, cnt, cand, out_q, out_idx, lpart);
  k_loss          <<<1,               256, 0, stream>>>(lpart, out);
}

// Round 12
// 207.869 us; speedup vs baseline: 1.4414x; 1.0040x over previous
//
#include <hip/hip_runtime.h>
#include <hip/hip_bf16.h>
#include <math.h>

// VQ quantizer: LDS-free register-sweep bf16-MFMA prefilter + fp32-chain-exact rescore.
//   Exact semantics (validated r2/r4/r6): dist = fl32(fl32(r2+e2) - 2*fma_chain(x.e)),
//   argmin first-min-wins.
// Swapped-operand MFMA: mfma(A=cb_frag, B=z_frag) puts z-row on lane&15 ->
//   per-row running min is in-lane fmin + 2 shfl (no LDS, no barriers).
// Capture rule (r11-validated): s(c) <= runmin + M; runmin = per-row prefix min,
//   cross-wave shared via device atomicMin(rowMinU). Any shared value >= true min
//   -> superset of all c with s_mfma(c) <= gmin + 2delta (~3e-4 <= M=5e-4); stale
//   reads only loosen -> safe. CAP=128; exact full-scan fallback on overflow.
// Round 12: register double-buffered cb fragments (pair-unrolled A0/A1) to hide
//   L2 latency under the MFMA block; float4-vectorized rescore chain.
// Outputs (float32 flat): [loss | quantized(8192*256) | indices(8192 as float)]

#define NROWS 8192
#define DDIM  256
#define KCW   8192
#define CAP   128
#define MARGIN 5e-4f

typedef __attribute__((ext_vector_type(8))) short short8;
typedef __attribute__((ext_vector_type(4))) float f32x4;

struct AFrag { short8 v[8]; f32x4 e2; };

__device__ inline unsigned fmap(float f) {
  unsigned b = __float_as_uint(f);
  return (b & 0x80000000u) ? ~b : (b | 0x80000000u);
}
__device__ inline float funmap(unsigned u) {
  unsigned b = (u & 0x80000000u) ? (u & 0x7FFFFFFFu) : ~u;
  return __uint_as_float(b);
}

// Fused: bf16 cast + e2 (f64->f32, cb rows) + rowMinU/cnt init (z rows).
__global__ __launch_bounds__(256) void k_prep_cast(const float* __restrict__ z,
                                                   const float* __restrict__ cb,
                                                   ushort* __restrict__ zb,
                                                   ushort* __restrict__ cbb,
                                                   float* __restrict__ e2f,
                                                   unsigned* __restrict__ rowMinU,
                                                   unsigned* __restrict__ cnt) {
  int t = threadIdx.x, w = t >> 6, lane = t & 63;
  int wid = blockIdx.x * 4 + w;           // 0..16383
  bool isCb = wid >= NROWS;
  int row = isCb ? wid - NROWS : wid;
  const float* src = (isCb ? cb : z) + (size_t)row * DDIM + lane * 4;
  float4 v = *reinterpret_cast<const float4*>(src);
  ushort4 o;
  __hip_bfloat16 bx = __float2bfloat16(v.x); o.x = *(ushort*)&bx;
  __hip_bfloat16 by = __float2bfloat16(v.y); o.y = *(ushort*)&by;
  __hip_bfloat16 bz = __float2bfloat16(v.z); o.z = *(ushort*)&bz;
  __hip_bfloat16 bw = __float2bfloat16(v.w); o.w = *(ushort*)&bw;
  ushort* dst = (isCb ? cbb : zb) + (size_t)row * DDIM + lane * 4;
  *reinterpret_cast<ushort4*>(dst) = o;
  if (isCb) {
    double d = (double)v.x * v.x + (double)v.y * v.y + (double)v.z * v.z + (double)v.w * v.w;
#pragma unroll
    for (int off = 1; off < 64; off <<= 1) d += __shfl_xor(d, off);
    if (lane == 0) e2f[row] = (float)d;
  } else {
    if (lane == 0) { rowMinU[row] = ~0u; cnt[row] = 0; }
  }
}

// Wave: 64 z-rows (4 n-frags x 16 on lane&15), sweeps 512 cb-cols (32 tiles of 16).
// z resident in VGPRs; cb fragments register-double-buffered (A0/A1) so tile t+1's
// global loads are in flight during tile t's MFMA block. No LDS, no barriers.
__global__ __launch_bounds__(256, 2) void k_sweep(const ushort* __restrict__ zb,
                                                  const ushort* __restrict__ cbb,
                                                  const float* __restrict__ e2f,
                                                  unsigned* __restrict__ rowMinU,
                                                  unsigned* __restrict__ cnt,
                                                  ushort* __restrict__ cand) {
  int t = threadIdx.x, w = t >> 6, lane = t & 63;
  int wid = blockIdx.x * 4 + w;           // 0..2047
  int rg = wid >> 4, sg = wid & 15;
  int R0 = rg * 64, C0 = sg * 512;
  int cl = lane & 15, g = lane >> 4;

  // z preload: B-frag layout (z-row on cl, k = kk*32 + g*8)
  short8 Z[4][8];
#pragma unroll
  for (int n = 0; n < 4; ++n)
#pragma unroll
    for (int kk = 0; kk < 8; ++kk)
      Z[n][kk] = *reinterpret_cast<const short8*>(
          &zb[(size_t)(R0 + n * 16 + cl) * DDIM + kk * 32 + g * 8]);

  int rowIdx[4];
#pragma unroll
  for (int n = 0; n < 4; ++n) rowIdx[n] = R0 + n * 16 + cl;

  float runm[4] = {INFINITY, INFINITY, INFINITY, INFINITY};

  auto LOADA = [&](AFrag& A, int tile) {
    int CT = C0 + tile * 16;
#pragma unroll
    for (int kk = 0; kk < 8; ++kk)
      A.v[kk] = *reinterpret_cast<const short8*>(
          &cbb[(size_t)(CT + cl) * DDIM + kk * 32 + g * 8]);
    A.e2 = *reinterpret_cast<const f32x4*>(&e2f[CT + g * 4]);
  };

  auto COMPUTE = [&](const AFrag& A, int tile) {
    int CT = C0 + tile * 16;
    f32x4 acc[4];
#pragma unroll
    for (int n = 0; n < 4; ++n) acc[n] = (f32x4){0.f, 0.f, 0.f, 0.f};
#pragma unroll
    for (int kk = 0; kk < 8; ++kk)
#pragma unroll
      for (int n = 0; n < 4; ++n)
        acc[n] = __builtin_amdgcn_mfma_f32_16x16x32_bf16(A.v[kk], Z[n][kk], acc[n], 0, 0, 0);

    // D layout: M-idx (cb-col offset) = g*4+j, N-idx (z-row) = cl
#pragma unroll
    for (int n = 0; n < 4; ++n) {
      float s0 = __fsub_rn(A.e2[0], __fmul_rn(2.0f, acc[n][0]));
      float s1 = __fsub_rn(A.e2[1], __fmul_rn(2.0f, acc[n][1]));
      float s2 = __fsub_rn(A.e2[2], __fmul_rn(2.0f, acc[n][2]));
      float s3 = __fsub_rn(A.e2[3], __fmul_rn(2.0f, acc[n][3]));
      float jm = fminf(fminf(s0, s1), fminf(s2, s3));
      jm = fminf(jm, __shfl_xor(jm, 16));   // reduce over g (4 lanes, same cl)
      jm = fminf(jm, __shfl_xor(jm, 32));
      runm[n] = fminf(runm[n], jm);
      float thr = runm[n] + MARGIN;
      int row = rowIdx[n];
      int colb = CT + g * 4;
      if (s0 <= thr) { unsigned sl = atomicAdd(&cnt[row], 1u); if (sl < CAP) cand[(size_t)row * CAP + sl] = (ushort)(colb + 0); }
      if (s1 <= thr) { unsigned sl = atomicAdd(&cnt[row], 1u); if (sl < CAP) cand[(size_t)row * CAP + sl] = (ushort)(colb + 1); }
      if (s2 <= thr) { unsigned sl = atomicAdd(&cnt[row], 1u); if (sl < CAP) cand[(size_t)row * CAP + sl] = (ushort)(colb + 2); }
      if (s3 <= thr) { unsigned sl = atomicAdd(&cnt[row], 1u); if (sl < CAP) cand[(size_t)row * CAP + sl] = (ushort)(colb + 3); }
    }

    // cross-wave threshold sharing (early-heavy cadence: tiles 0,1,7,15,23,31)
    if (tile < 2 || (tile & 7) == 7) {
#pragma unroll
      for (int n = 0; n < 4; ++n) {
        if (g == n) atomicMin(&rowMinU[rowIdx[n]], fmap(runm[n]));
      }
#pragma unroll
      for (int n = 0; n < 4; ++n)
        runm[n] = fminf(runm[n], funmap(rowMinU[rowIdx[n]]));   // stale -> looser -> safe
    }
  };

  AFrag A0, A1;
  LOADA(A0, 0);
  for (int tile = 0; tile < 32; tile += 2) {     // pair-unrolled: no reg moves
    if (tile + 1 < 32) LOADA(A1, tile + 1);      // in flight during COMPUTE(A0)
    COMPUTE(A0, tile);
    if (tile + 2 < 32) LOADA(A0, tile + 2);      // in flight during COMPUTE(A1)
    COMPUTE(A1, tile + 1);
  }
}

// Fused: exact fp32-chain rescore (lex (s,idx) min = first-min-wins) + overflow
// full-scan fallback + gather + per-row loss partial. r2 computed inline.
// Chain loads vectorized to float4 (same IEEE order: x,y,z,w sequential FMAs).
__global__ __launch_bounds__(256) void k_rescore_gather(const float* __restrict__ z,
                                                        const float* __restrict__ cb,
                                                        const float* __restrict__ e2f,
                                                        const unsigned* __restrict__ cnt,
                                                        const ushort* __restrict__ cand,
                                                        float* __restrict__ out_q,
                                                        float* __restrict__ out_idx,
                                                        float* __restrict__ lpart) {
  int t = threadIdx.x, w = t >> 6, lane = t & 63;
  int row = blockIdx.x * 4 + w;
  const float* xp = z + (size_t)row * DDIM;
  const float4* xp4 = reinterpret_cast<const float4*>(xp);
  float4 x4 = xp4[lane];
  double rd = (double)x4.x * x4.x + (double)x4.y * x4.y + (double)x4.z * x4.z + (double)x4.w * x4.w;
#pragma unroll
  for (int off = 1; off < 64; off <<= 1) rd += __shfl_xor(rd, off);
  float r2v = (float)rd;                  // same summation as r6's k_prep (validated)

  unsigned n = cnt[row];
  float s = INFINITY; int ci = 0x7fffffff;
  if (n <= CAP) {
#pragma unroll
    for (int base = 0; base < CAP; base += 64) {
      int k_i = base + lane;
      if (k_i < (int)n) {
        int c = cand[(size_t)row * CAP + k_i];
        const float4* ep4 = reinterpret_cast<const float4*>(cb + (size_t)c * DDIM);
        float acc = 0.f;
#pragma unroll 4
        for (int k4 = 0; k4 < 64; ++k4) {          // k ascending, exact chain order
          float4 e = ep4[k4], x = xp4[k4];
          acc = __fmaf_rn(x.x, e.x, acc);
          acc = __fmaf_rn(x.y, e.y, acc);
          acc = __fmaf_rn(x.z, e.z, acc);
          acc = __fmaf_rn(x.w, e.w, acc);
        }
        float scv = __fsub_rn(__fadd_rn(r2v, e2f[c]), __fmul_rn(2.0f, acc));
        if (scv < s || (scv == s && c < ci)) { s = scv; ci = c; }
      }
    }
  } else {
    for (int base = 0; base < KCW; base += 64) {   // exact full-scan fallback
      int c = base + lane;
      const float4* ep4 = reinterpret_cast<const float4*>(cb + (size_t)c * DDIM);
      float acc = 0.f;
#pragma unroll 4
      for (int k4 = 0; k4 < 64; ++k4) {
        float4 e = ep4[k4], x = xp4[k4];
        acc = __fmaf_rn(x.x, e.x, acc);
        acc = __fmaf_rn(x.y, e.y, acc);
        acc = __fmaf_rn(x.z, e.z, acc);
        acc = __fmaf_rn(x.w, e.w, acc);
      }
      float scv = __fsub_rn(__fadd_rn(r2v, e2f[c]), __fmul_rn(2.0f, acc));
      if (scv < s) { s = scv; ci = c; }            // c ascending: first-wins
    }
  }
#pragma unroll
  for (int off = 1; off < 64; off <<= 1) {         // butterfly: all lanes get min
    float os = __shfl_xor(s, off); int oi = __shfl_xor(ci, off);
    if (os < s || (os == s && oi < ci)) { s = os; ci = oi; }
  }
  if (lane == 0) out_idx[row] = (float)ci;

  float4 qv = *reinterpret_cast<const float4*>(cb + (size_t)ci * DDIM + lane * 4);
  float* o = out_q + (size_t)row * DDIM + lane * 4; // out+1 base: scalar stores
  o[0] = qv.x; o[1] = qv.y; o[2] = qv.z; o[3] = qv.w;
  float dx = qv.x - x4.x, dy = qv.y - x4.y, dz = qv.z - x4.z, dw = qv.w - x4.w;
  double d = (double)dx * dx + (double)dy * dy + (double)dz * dz + (double)dw * dw;
#pragma unroll
  for (int off = 1; off < 64; off <<= 1) d += __shfl_xor(d, off);
  if (lane == 0) lpart[row] = (float)d;
}

__global__ __launch_bounds__(256) void k_loss(const float* __restrict__ lpart,
                                              float* __restrict__ out0) {
  __shared__ double red[256];
  int t = threadIdx.x;
  double s = 0.0;
  for (int j = t; j < NROWS; j += 256) s += lpart[j];  // fixed order -> deterministic
  red[t] = s;
  __syncthreads();
  for (int off = 128; off > 0; off >>= 1) {
    if (t < off) red[t] += red[t + off];
    __syncthreads();
  }
  if (t == 0) out0[0] = (float)(1.25 * red[0] / (double)((size_t)NROWS * DDIM));
}

extern "C" void kernel_launch(void* const* d_in, const int* in_sizes, int n_in,
                              void* d_out, int out_size, void* d_ws, size_t ws_size,
                              hipStream_t stream) {
  const float* z  = (const float*)d_in[0];   // [16,512,256] flat
  const float* cb = (const float*)d_in[1];   // [8192,256]
  float* out = (float*)d_out;
  char* ws = (char*)d_ws;
  const size_t HALF = (size_t)NROWS * DDIM;  // 2,097,152

  // bf16 copies in the out_q region (out+4 floats: 16B-aligned). Last 3 floats
  // of cbb overlap out_idx[0..2]; out_idx is written by k_rescore_gather, which
  // runs after the last zb/cbb read (k_sweep). Recomputed every call.
  ushort* zb  = (ushort*)(out + 4);
  ushort* cbb = zb + HALF;

  // ws: e2f 32K | cnt 32K | rowMinU 32K (lpart overlays it after k_sweep) |
  //     cand ushort 8192*128*2 = 2MB ; total 2,195,456 B (< 2,211,840 proven in r2)
  size_t off = 0;
  float*    e2f     = (float*)(ws + off);    off += NROWS * 4;
  unsigned* cnt     = (unsigned*)(ws + off); off += NROWS * 4;
  unsigned* rowMinU = (unsigned*)(ws + off);
  float*    lpart   = (float*)(ws + off);    off += NROWS * 4;   // overlays rowMinU
  ushort*   cand    = (ushort*)(ws + off);   off += (size_t)NROWS * CAP * 2;

  float* out_q   = out + 1;
  float* out_idx = out + 1 + HALF;

  k_prep_cast     <<<(2 * NROWS) / 4, 256, 0, stream>>>(z, cb, zb, cbb, e2f, rowMinU, cnt);
  k_sweep         <<<512,             256, 0, stream>>>(zb, cbb, e2f, rowMinU, cnt, cand);
  k_rescore_gather<<<NROWS / 4,       256, 0, stream>>>(z, cb, e2f, cnt, cand, out_q, out_idx, lpart);
  k_loss          <<<1,               256, 0, stream>>>(lpart, out);
}